// Round 1
// 111.611 us; speedup vs baseline: 1.1795x; 1.1795x over previous
//
#include <hip/hip_runtime.h>

// Problem constants (B=2, T=1024, C=256, H=128, HD=2). All I/O is float32.
#define T_SEQ   1024
#define C_DIM   256
#define H_HEADS 128
#define NTOK    2048   // B*T
#define BH      256    // B*H

typedef unsigned short u16;
typedef unsigned int   u32;
typedef __attribute__((ext_vector_type(8))) short bf16x8;  // MFMA A/B frag
typedef __attribute__((ext_vector_type(4))) float f32x4;   // MFMA C/D frag
typedef __attribute__((ext_vector_type(2))) float f32x2;   // packed f32 (v_pk_*)

typedef __attribute__((address_space(1))) u32 gu32;  // global
typedef __attribute__((address_space(3))) u32 lu32;  // LDS

__device__ __forceinline__ float bf2f(u16 u) {
  return __uint_as_float(((u32)u) << 16);
}
__device__ __forceinline__ u16 f2bf(float f) {  // RNE (no NaN in this problem)
  u32 u = __float_as_uint(f);
  u32 r = u + 0x7fffu + ((u >> 16) & 1u);
  return (u16)(r >> 16);
}

// ---------------------------------------------------------------------------
// Packed operand format: every matrix [R][256] fp32 is split into hi/lo bf16
// planes stored as 64x64 tile images (8192 B each), tile index = tr*4 + kc.
// Within a tile, element (r,c) lives at byte (r*128 + c*2) ^ ((r&7)<<4).
// The XOR swizzle spreads a 16-lane column read across 8 bank groups
// (2-way = free, m136) and is PRE-BAKED into the global image so that
// global_load_lds (linear dest, base+lane*16) reproduces it in LDS exactly
// (rule #21: same involution on source and read side, dest stays linear).
// 32-row halves of a tile are contiguous 4096-B blocks and preserve r&7.
// ---------------------------------------------------------------------------

// async 1 KiB segment: per-lane global addr, wave-uniform LDS base
__device__ __forceinline__ void gl_seg(const u16* g, u16* l, int lane) {
  __builtin_amdgcn_global_load_lds((gu32*)(g + lane * 8), (lu32*)l, 16, 0, 0);
}

// 16B fragment read from a swizzled LDS tile plane (row-major 128 B rows)
__device__ __forceinline__ bf16x8 ldsf(const u16* plane, int row, int kk) {
  int off = (row * 128 + kk * 2) ^ ((row & 7) << 4);
  return *(const bf16x8*)((const char*)plane + off);
}

// ---------------------------------------------------------------------------
// Kernel 0: pack x (128 tiles), w_qkv (48 tiles), w_proj (16 tiles) into
// swizzled hi/lo bf16 tile images. One block per 64x64 tile, 192 blocks.
// hi = RNE(x), lo = RNE(x - hi)  (identical arithmetic to the verified hilo
// split, so GEMM results are bit-compatible with the previous version).
// ---------------------------------------------------------------------------
__global__ __launch_bounds__(256) void k_pack(
    const float* __restrict__ x, const float* __restrict__ wq,
    const float* __restrict__ wp,
    u16* __restrict__ xh, u16* __restrict__ xl,
    u16* __restrict__ wqh, u16* __restrict__ wql,
    u16* __restrict__ wph, u16* __restrict__ wpl)
{
  const int bid = blockIdx.x, tid = threadIdx.x;
  const float* src; u16 *dh, *dl; int ti;
  if (bid < 128)      { src = x;  dh = xh;  dl = xl;  ti = bid; }
  else if (bid < 176) { src = wq; dh = wqh; dl = wql; ti = bid - 128; }
  else                { src = wp; dh = wph; dl = wpl; ti = bid - 176; }
  const int tr = ti >> 2, kc = ti & 3;
  char* bh = (char*)dh + (size_t)ti * 8192;
  char* bl = (char*)dl + (size_t)ti * 8192;
#pragma unroll
  for (int it = 0; it < 4; ++it) {
    int idx = it * 256 + tid;
    int r = idx >> 4, c4 = (idx & 15) * 4;
    float4 g = *(const float4*)&src[(tr * 64 + r) * C_DIM + kc * 64 + c4];
    ushort4 h4, l4;
    h4.x = f2bf(g.x); l4.x = f2bf(g.x - bf2f(h4.x));
    h4.y = f2bf(g.y); l4.y = f2bf(g.y - bf2f(h4.y));
    h4.z = f2bf(g.z); l4.z = f2bf(g.z - bf2f(h4.z));
    h4.w = f2bf(g.w); l4.w = f2bf(g.w - bf2f(h4.w));
    int off = (r * 128 + c4 * 2) ^ ((r & 7) << 4);
    *(ushort4*)(bh + off) = h4;
    *(ushort4*)(bl + off) = l4;
  }
}

// ---------------------------------------------------------------------------
// Kernel 1: qkv = x @ w_qkv^T (M=2048, N=768, K=256) from packed operands.
// Tile 32x64, grid (64,12)=768 blocks (3/CU). Double-buffered LDS with
// global_load_lds prefetch: stage chunk kc+1, compute chunk kc, syncthreads.
// D = Alo*Bhi + Ahi*Blo + Ahi*Bhi (3-MFMA hilo). Fused RMSNorm epilogue.
// Fragment layout as verified: A/B row = lane&15, k = (lane>>4)*8+j;
// C/D col = lane&15, row = (lane>>4)*4+i.
// ---------------------------------------------------------------------------
__global__ __launch_bounds__(256) void k_qkv(
    const u16* __restrict__ xh, const u16* __restrict__ xl,
    const u16* __restrict__ wh, const u16* __restrict__ wl,
    const float* __restrict__ qnw, const float* __restrict__ knw,
    float* __restrict__ q, float* __restrict__ kv)
{
  // per buffer: Xhi 2048, Xlo 2048, Whi 4096, Wlo 4096 u16 = 24 KiB; x2 = 48 KiB
  __shared__ __align__(16) u16 lds[2][12288];

  const int tid  = threadIdx.x;
  const int lane = tid & 63;
  const int w    = tid >> 6;
  const int bx   = blockIdx.x, by = blockIdx.y;
  const int row0 = bx * 32, col0 = by * 64;
  const int xtb  = (bx >> 1) * 4;      // x tile base (tiles are 64 rows)
  const int xho  = (bx & 1) * 2048;    // 32-row half offset, u16 units
  const int wtb  = by * 4;             // w_qkv tile base (full 64-row tile)
  const int fr   = lane & 15;
  const int ko   = (lane >> 4) * 8;

  f32x4 acc[2] = {};

  auto STAGE = [&](int kc, int b) {
    const u16* gxh = xh + (xtb + kc) * 4096 + xho;
    const u16* gxl = xl + (xtb + kc) * 4096 + xho;
    const u16* gwh = wh + (wtb + kc) * 4096;
    const u16* gwl = wl + (wtb + kc) * 4096;
    u16* L = lds[b];
    gl_seg(gxh + w * 512,        L + w * 512,               lane);
    gl_seg(gxl + w * 512,        L + 2048 + w * 512,        lane);
    gl_seg(gwh + w * 512,        L + 4096 + w * 512,        lane);
    gl_seg(gwh + (w + 4) * 512,  L + 4096 + (w + 4) * 512,  lane);
    gl_seg(gwl + w * 512,        L + 8192 + w * 512,        lane);
    gl_seg(gwl + (w + 4) * 512,  L + 8192 + (w + 4) * 512,  lane);
  };

  STAGE(0, 0);
  __syncthreads();
  for (int kc = 0; kc < 4; ++kc) {
    if (kc < 3) STAGE(kc + 1, (kc + 1) & 1);   // prefetch next chunk
    const u16* L   = lds[kc & 1];
    const u16* bXh = L;
    const u16* bXl = L + 2048;
    const u16* bWh = L + 4096;
    const u16* bWl = L + 8192;
#pragma unroll
    for (int ks = 0; ks < 2; ++ks) {
      const int kk = ks * 32 + ko;
      bf16x8 bhi = ldsf(bWh, w * 16 + fr, kk);
      bf16x8 blo = ldsf(bWl, w * 16 + fr, kk);
#pragma unroll
      for (int rt = 0; rt < 2; ++rt) {
        bf16x8 ahi = ldsf(bXh, rt * 16 + fr, kk);
        bf16x8 alo = ldsf(bXl, rt * 16 + fr, kk);
        acc[rt] = __builtin_amdgcn_mfma_f32_16x16x32_bf16(alo, bhi, acc[rt], 0, 0, 0);
        acc[rt] = __builtin_amdgcn_mfma_f32_16x16x32_bf16(ahi, blo, acc[rt], 0, 0, 0);
        acc[rt] = __builtin_amdgcn_mfma_f32_16x16x32_bf16(ahi, bhi, acc[rt], 0, 0, 0);
      }
    }
    __syncthreads();   // drains vmcnt (prefetch partially overlapped) + barrier
  }

  // epilogue: section uniform per block (col0 multiple of 64, sections 256)
  const int sec = col0 >> 8;                       // 0=q, 1=k, 2=v
  const int cg  = col0 + w * 16 + fr;              // global col
  const int d   = cg & 1;
  const int h   = (cg & 255) >> 1;
  const float wn = (sec == 0) ? qnw[d] : (sec == 1) ? knw[d] : 1.f;

#pragma unroll
  for (int rt = 0; rt < 2; ++rt) {
#pragma unroll
    for (int i = 0; i < 4; ++i) {
      float val = acc[rt][i];
      int n = row0 + rt * 16 + (lane >> 4) * 4 + i;   // token
      int b = n >> 10, t = n & 1023;
      int bh = b * H_HEADS + h;
      if (sec < 2) {
        float pv = __shfl_xor(val, 1);                // partner col of the pair
        float rr = rsqrtf(0.5f * (val * val + pv * pv) + 1e-6f);
        val = val * rr * wn;
      }
      if (sec == 0)      q [(bh * T_SEQ + t) * 2 + d]     = val;
      else if (sec == 1) kv[(bh * T_SEQ + t) * 4 + d]     = val;
      else               kv[(bh * T_SEQ + t) * 4 + 2 + d] = val;
    }
  }
}

// ---------------------------------------------------------------------------
// Kernel 2: attention. Packed-f32 (v_pk_fma_f32) inner loop: two queries per
// f32x2. RMSNormed q,k bound |score*scale| <= sqrt2 -> single-pass softmax.
// Epilogue writes y directly as packed/swizzled hi/lo bf16 tiles for k_proj.
// ---------------------------------------------------------------------------
__global__ __launch_bounds__(256) void k_attn(
    const float* __restrict__ q, const float* __restrict__ kv,
    u16* __restrict__ yh, u16* __restrict__ yl)
{
  __shared__ float4 skv[T_SEQ];         // 16 KB
  __shared__ float  red[4][256][3];     // 12 KB

  const int tid  = threadIdx.x;
  const int head = blockIdx.x;          // 0..255
  const int g    = 3 - blockIdx.y;      // heavy groups dispatched first
  const int qb   = g * 256;
  const int S    = qb + 256;
  const int lane = tid & 63;
  const int w    = tid >> 6;

  const float4* kvh = (const float4*)(kv + head * (T_SEQ * 4));
  for (int i = tid; i < S; i += 256) skv[i] = kvh[i];

  const float LS = 0.70710678118f * 1.44269504089f;  // scale * log2(e)
  float qxs[4], qys[4];
#pragma unroll
  for (int j = 0; j < 4; ++j) {
    int t = qb + j * 64 + lane;
    float2 qv = *(const float2*)&q[(head * T_SEQ + t) * 2];
    qxs[j] = qv.x * LS;
    qys[j] = qv.y * LS;
  }
  f32x2 qx01 = {qxs[0], qxs[1]}, qx23 = {qxs[2], qxs[3]};
  f32x2 qy01 = {qys[0], qys[1]}, qy23 = {qys[2], qys[3]};
  __syncthreads();

  f32x2 den01 = {0.f, 0.f}, den23 = {0.f, 0.f};
  f32x2 nx01  = {0.f, 0.f}, nx23  = {0.f, 0.f};
  f32x2 ny01  = {0.f, 0.f}, ny23  = {0.f, 0.f};

  // bulk: keys [0, qb), no mask needed (s < qb <= tq[j] always)
  const int cb = qb >> 2;
  const int b0 = w * cb, b1 = b0 + cb;
#pragma unroll 2
  for (int s = b0; s < b1; ++s) {
    float4 kvv = skv[s];
    f32x2 kx = {kvv.x, kvv.x}, ky = {kvv.y, kvv.y};
    f32x2 kz = {kvv.z, kvv.z}, kw = {kvv.w, kvv.w};
    f32x2 s01 = __builtin_elementwise_fma(qx01, kx, qy01 * ky);
    f32x2 s23 = __builtin_elementwise_fma(qx23, kx, qy23 * ky);
    f32x2 e01 = { __builtin_amdgcn_exp2f(s01.x), __builtin_amdgcn_exp2f(s01.y) };
    f32x2 e23 = { __builtin_amdgcn_exp2f(s23.x), __builtin_amdgcn_exp2f(s23.y) };
    den01 += e01; den23 += e23;
    nx01 = __builtin_elementwise_fma(e01, kz, nx01);
    nx23 = __builtin_elementwise_fma(e23, kz, nx23);
    ny01 = __builtin_elementwise_fma(e01, kw, ny01);
    ny23 = __builtin_elementwise_fma(e23, kw, ny23);
  }
  // diagonal: keys [qb + w*64, +64), causal mask applies
  const int d0  = qb + w * 64;
  const int tqL = qb + lane;
#pragma unroll 2
  for (int s = d0; s < d0 + 64; ++s) {
    float4 kvv = skv[s];
    f32x2 kx = {kvv.x, kvv.x}, ky = {kvv.y, kvv.y};
    f32x2 kz = {kvv.z, kvv.z}, kw = {kvv.w, kvv.w};
    f32x2 s01 = __builtin_elementwise_fma(qx01, kx, qy01 * ky);
    f32x2 s23 = __builtin_elementwise_fma(qx23, kx, qy23 * ky);
    f32x2 e01 = { __builtin_amdgcn_exp2f(s01.x), __builtin_amdgcn_exp2f(s01.y) };
    f32x2 e23 = { __builtin_amdgcn_exp2f(s23.x), __builtin_amdgcn_exp2f(s23.y) };
    e01.x = (s <= tqL)       ? e01.x : 0.f;
    e01.y = (s <= tqL + 64)  ? e01.y : 0.f;
    e23.x = (s <= tqL + 128) ? e23.x : 0.f;
    e23.y = (s <= tqL + 192) ? e23.y : 0.f;
    den01 += e01; den23 += e23;
    nx01 = __builtin_elementwise_fma(e01, kz, nx01);
    nx23 = __builtin_elementwise_fma(e23, kz, nx23);
    ny01 = __builtin_elementwise_fma(e01, kw, ny01);
    ny23 = __builtin_elementwise_fma(e23, kw, ny23);
  }

  red[w][lane][0]       = den01.x; red[w][lane][1]       = nx01.x; red[w][lane][2]       = ny01.x;
  red[w][64 + lane][0]  = den01.y; red[w][64 + lane][1]  = nx01.y; red[w][64 + lane][2]  = ny01.y;
  red[w][128 + lane][0] = den23.x; red[w][128 + lane][1] = nx23.x; red[w][128 + lane][2] = ny23.x;
  red[w][192 + lane][0] = den23.y; red[w][192 + lane][1] = nx23.y; red[w][192 + lane][2] = ny23.y;
  __syncthreads();

  // thread tid finalizes query qb+tid; write y as packed hi/lo bf16 tile image
  float dd = 0.f, ax = 0.f, ay = 0.f;
#pragma unroll
  for (int ww = 0; ww < 4; ++ww) {
    dd += red[ww][tid][0];
    ax += red[ww][tid][1];
    ay += red[ww][tid][2];
  }
  float inv = 1.f / dd;
  float ox = ax * inv, oy = ay * inv;
  int b = head >> 7, hh = head & 127;
  int t = qb + tid;
  int n = b * T_SEQ + t;              // y row (0..2047)
  int c = hh * 2;                     // y col (even)
  int tile = (n >> 6) * 4 + (c >> 6);
  int r = n & 63, cc = c & 63;
  int off = (r * 128 + cc * 2) ^ ((r & 7) << 4);
  u16 hx = f2bf(ox); float rx = ox - bf2f(hx);
  u16 hy = f2bf(oy); float ry = oy - bf2f(hy);
  *(u32*)((char*)yh + (size_t)tile * 8192 + off) = (u32)hx | ((u32)hy << 16);
  *(u32*)((char*)yl + (size_t)tile * 8192 + off) = (u32)f2bf(rx) | ((u32)f2bf(ry) << 16);
}

// ---------------------------------------------------------------------------
// Kernel 3: out = y @ w_proj^T (M=2048, N=256, K=256) from packed operands.
// Tile 32x32, grid (64,8)=512 blocks (2/CU). Wave w -> 16x16 sub-tile
// (row-half w>>1, col-half w&1). Same prefetch structure as k_qkv.
// ---------------------------------------------------------------------------
__global__ __launch_bounds__(256) void k_proj(
    const u16* __restrict__ yh, const u16* __restrict__ yl,
    const u16* __restrict__ wh, const u16* __restrict__ wl,
    float* __restrict__ out)
{
  // per buffer: Xhi/Xlo/Whi/Wlo 2048 u16 each = 16 KiB; x2 = 32 KiB
  __shared__ __align__(16) u16 lds[2][8192];

  const int tid  = threadIdx.x;
  const int lane = tid & 63;
  const int w    = tid >> 6;
  const int bx   = blockIdx.x, by = blockIdx.y;
  const int row0 = bx * 32, col0 = by * 32;
  const int ytb  = (bx >> 1) * 4;
  const int yho  = (bx & 1) * 2048;
  const int wtb  = (by >> 1) * 4;
  const int who  = (by & 1) * 2048;
  const int fr   = lane & 15;
  const int ko   = (lane >> 4) * 8;

  f32x4 acc = {};

  auto STAGE = [&](int kc, int b) {
    u16* L = lds[b];
    gl_seg(yh + (ytb + kc) * 4096 + yho + w * 512, L + w * 512,        lane);
    gl_seg(yl + (ytb + kc) * 4096 + yho + w * 512, L + 2048 + w * 512, lane);
    gl_seg(wh + (wtb + kc) * 4096 + who + w * 512, L + 4096 + w * 512, lane);
    gl_seg(wl + (wtb + kc) * 4096 + who + w * 512, L + 6144 + w * 512, lane);
  };

  STAGE(0, 0);
  __syncthreads();
  const int ar = (w >> 1) * 16 + fr;   // A row local (token)
  const int br = (w & 1) * 16 + fr;    // B row local (out col)
  for (int kc = 0; kc < 4; ++kc) {
    if (kc < 3) STAGE(kc + 1, (kc + 1) & 1);
    const u16* L = lds[kc & 1];
#pragma unroll
    for (int ks = 0; ks < 2; ++ks) {
      const int kk = ks * 32 + ko;
      bf16x8 bhi = ldsf(L + 4096, br, kk);
      bf16x8 blo = ldsf(L + 6144, br, kk);
      bf16x8 ahi = ldsf(L,        ar, kk);
      bf16x8 alo = ldsf(L + 2048, ar, kk);
      acc = __builtin_amdgcn_mfma_f32_16x16x32_bf16(alo, bhi, acc, 0, 0, 0);
      acc = __builtin_amdgcn_mfma_f32_16x16x32_bf16(ahi, blo, acc, 0, 0, 0);
      acc = __builtin_amdgcn_mfma_f32_16x16x32_bf16(ahi, bhi, acc, 0, 0, 0);
    }
    __syncthreads();
  }

  const int cg = col0 + (w & 1) * 16 + fr;
#pragma unroll
  for (int i = 0; i < 4; ++i) {
    int n = row0 + (w >> 1) * 16 + (lane >> 4) * 4 + i;
    out[n * C_DIM + cg] = acc[i];
  }
}

// ---------------------------------------------------------------------------
extern "C" void kernel_launch(void* const* d_in, const int* in_sizes, int n_in,
                              void* d_out, int out_size, void* d_ws, size_t ws_size,
                              hipStream_t stream) {
  const float* x     = (const float*)d_in[0];
  const float* wqkv  = (const float*)d_in[1];
  const float* wproj = (const float*)d_in[2];
  const float* qnw   = (const float*)d_in[3];
  const float* knw   = (const float*)d_in[4];

  char* p = (char*)d_ws;
  float* q  = (float*)p;  p += (size_t)BH * T_SEQ * 2 * 4;   // 2 MB
  float* kv = (float*)p;  p += (size_t)BH * T_SEQ * 4 * 4;   // 4 MB
  u16* xh  = (u16*)p;     p += (size_t)NTOK  * C_DIM * 2;    // 1 MB each
  u16* xl  = (u16*)p;     p += (size_t)NTOK  * C_DIM * 2;
  u16* wqh = (u16*)p;     p += (size_t)768   * C_DIM * 2;
  u16* wql = (u16*)p;     p += (size_t)768   * C_DIM * 2;
  u16* wph = (u16*)p;     p += (size_t)C_DIM * C_DIM * 2;
  u16* wpl = (u16*)p;     p += (size_t)C_DIM * C_DIM * 2;
  u16* yh  = (u16*)p;     p += (size_t)NTOK  * C_DIM * 2;
  u16* yl  = (u16*)p;     p += (size_t)NTOK  * C_DIM * 2;

  k_pack<<<192, 256, 0, stream>>>(x, wqkv, wproj, xh, xl, wqh, wql, wph, wpl);
  k_qkv <<<dim3(64, 12), 256, 0, stream>>>(xh, xl, wqh, wql, qnw, knw, q, kv);
  k_attn<<<dim3(BH, 4),  256, 0, stream>>>(q, kv, yh, yl);
  k_proj<<<dim3(64, 8),  256, 0, stream>>>(yh, yl, wph, wpl, (float*)d_out);
}